// Round 11
// baseline (183.302 us; speedup 1.0000x reference)
//
#include <hip/hip_runtime.h>

// Lucas-Kanade sparse optical flow, 21x21 windows, Scharr gradients,
// Gaussian weights (sigma=2). B=16, H=W=1008, HS=WS=48, T=2304.
// Output: (B, T, 2, 2) float32 = [win_pos, vels].
//
// v6 = v1's lean scalar rolling window, but each thread runs TWO
// independent column streams (gx, gx+252): doubles the per-wave
// memory-level parallelism (2 independent load chains) while staying
// under the 64-VGPR / 8-waves-per-SIMD occupancy cliff.
// Grid: 16 batches x 48 window-rows x 2 half-strips = 1536 blocks.

constexpr int HH   = 1008;
constexpr int WW   = 1008;
constexpr int WINN = 21;
constexpr int HSN  = 48;
constexpr int WSN  = 48;
constexpr int TN   = HSN * WSN;        // 2304
constexpr int SEGS = 2;                // half-strips per window-row
constexpr int CPT  = 252;              // columns per stream-lane group
constexpr int COLS = 504;              // columns per block (2 streams)
constexpr int WPB  = 24;               // windows per block

// exp(-(y-10)^2/8) — constexpr: unrolled loop folds these to literals.
constexpr float kWY[WINN] = {
    3.7266532e-6f, 4.0065297e-5f, 3.3546262e-4f, 2.1874911e-3f,
    1.1108997e-2f, 4.3936934e-2f, 1.3533528e-1f, 3.2465247e-1f,
    6.0653066e-1f, 8.8249690e-1f, 1.0f,          8.8249690e-1f,
    6.0653066e-1f, 3.2465247e-1f, 1.3533528e-1f, 4.3936934e-2f,
    1.1108997e-2f, 2.1874911e-3f, 3.3546262e-4f, 4.0065297e-5f,
    3.7266532e-6f };

__global__ __launch_bounds__(256)
void SparseOptFlowLK_kernel(const float* __restrict__ imgs,
                            float* __restrict__ out) {
    const int bi  = blockIdx.x;                 // b*96 + hy*2 + seg
    const int b   = bi / (HSN * SEGS);
    const int rem = bi % (HSN * SEGS);
    const int hy  = rem / SEGS;                 // window-row 0..47
    const int seg = rem % SEGS;                 // half 0..1

    const float* __restrict__ ff = imgs + (size_t)b * (2ull * HH * WW);
    const float* __restrict__ sf = ff + (size_t)HH * WW;

    __shared__ float colsum[5][COLS];           // per-column partial sums
    __shared__ float red[WPB][5];               // per-window sums

    const int lx = threadIdx.x;

    if (lx < CPT) {
        const int ga = seg * COLS + lx;         // stream A column
        const int gb = ga + CPT;                // stream B column
        const bool hla = (ga > 0);
        const bool hrb = (gb < WW - 1);

        // x-weight: window-local col = lx % 21 for both streams (252 = 12*21)
        const float dxw = (float)(lx % WINN - 10);
        const float wxw = __expf(-dxw * dxw * 0.125f);

        const int g0 = hy * WINN;               // first window row (global)

        // two independent rolling 3x3 windows
        float am0, am1, am2, ac0, ac1, ac2;
        float bm0, bm1, bm2, bc0, bc1, bc2;
        if (g0 > 0) {
            const float* r = ff + (size_t)(g0 - 1) * WW;
            am1 = r[ga]; am0 = hla ? r[ga - 1] : 0.0f; am2 = r[ga + 1];
            bm1 = r[gb]; bm0 = r[gb - 1];              bm2 = hrb ? r[gb + 1] : 0.0f;
        } else {
            am0 = am1 = am2 = 0.0f;
            bm0 = bm1 = bm2 = 0.0f;             // SAME zero pad (top edge)
        }
        {
            const float* r = ff + (size_t)g0 * WW;
            ac1 = r[ga]; ac0 = hla ? r[ga - 1] : 0.0f; ac2 = r[ga + 1];
            bc1 = r[gb]; bc0 = r[gb - 1];              bc2 = hrb ? r[gb + 1] : 0.0f;
        }

        float aA = 0.f, aB = 0.f, aD = 0.f, aX = 0.f, aY = 0.f;
        float bA = 0.f, bB = 0.f, bD = 0.f, bX = 0.f, bY = 0.f;

        #pragma unroll
        for (int y = 0; y < WINN; ++y) {
            const int gp = g0 + y + 1;
            float ap0, ap1, ap2, bp0, bp1, bp2;
            if (gp < HH) {
                const float* r = ff + (size_t)gp * WW;
                ap1 = r[ga]; ap0 = hla ? r[ga - 1] : 0.0f; ap2 = r[ga + 1];
                bp1 = r[gb]; bp0 = r[gb - 1];              bp2 = hrb ? r[gb + 1] : 0.0f;
            } else {
                ap0 = ap1 = ap2 = 0.0f;
                bp0 = bp1 = bp2 = 0.0f;         // SAME zero pad (bottom edge)
            }
            const float* srow = sf + (size_t)(g0 + y) * WW;
            const float sfa = srow[ga];
            const float sfb = srow[gb];

            const float w = wxw * kWY[y];       // literal kWY[y]

            // stream A: Scharr (cross-correlation = XLA conv semantics)
            {
                const float Ix = 3.0f*(am2-am0) + 10.0f*(ac2-ac0) + 3.0f*(ap2-ap0);
                const float Iy = 3.0f*(ap0-am0) + 10.0f*(ap1-am1) + 3.0f*(ap2-am2);
                const float df = ac1 - sfa;
                const float wIx = w * Ix, wIy = w * Iy;
                aA += wIx * Ix;  aB += wIx * Iy;  aD += wIy * Iy;
                aX += wIx * df;  aY += wIy * df;
            }
            // stream B
            {
                const float Ix = 3.0f*(bm2-bm0) + 10.0f*(bc2-bc0) + 3.0f*(bp2-bp0);
                const float Iy = 3.0f*(bp0-bm0) + 10.0f*(bp1-bm1) + 3.0f*(bp2-bm2);
                const float df = bc1 - sfb;
                const float wIx = w * Ix, wIy = w * Iy;
                bA += wIx * Ix;  bB += wIx * Iy;  bD += wIy * Iy;
                bX += wIx * df;  bY += wIy * df;
            }

            am0 = ac0; am1 = ac1; am2 = ac2;
            ac0 = ap0; ac1 = ap1; ac2 = ap2;
            bm0 = bc0; bm1 = bc1; bm2 = bc2;
            bc0 = bp0; bc1 = bp1; bc2 = bp2;
        }

        colsum[0][lx] = aA;  colsum[0][lx + CPT] = bA;
        colsum[1][lx] = aB;  colsum[1][lx + CPT] = bB;
        colsum[2][lx] = aD;  colsum[2][lx + CPT] = bD;
        colsum[3][lx] = aX;  colsum[3][lx + CPT] = bX;
        colsum[4][lx] = aY;  colsum[4][lx + CPT] = bY;
    }
    __syncthreads();

    // reduce 21 columns -> per-window sums (24 windows x 5 sums = 120 thr)
    if (lx < WPB * 5) {
        const int w = lx / 5;
        const int s = lx % 5;
        float sum = 0.0f;
        #pragma unroll
        for (int j = 0; j < WINN; ++j) sum += colsum[s][w * WINN + j];
        red[w][s] = sum;
    }
    __syncthreads();

    // solve 2x2 per window and store
    if (lx < WPB) {
        const float A  = red[lx][0];
        const float Bv = red[lx][1];
        const float D  = red[lx][2];
        const float Bx = red[lx][3];
        const float By = red[lx][4];

        const float det = A * D - Bv * Bv;
        const float inv = (det != 0.0f) ? (1.0f / det) : 0.0f;
        const float vx  = inv * ( D * Bx - Bv * By);
        const float vy  = inv * (-Bv * Bx + A  * By);

        const int wxg = seg * WPB + lx;         // global window col 0..47
        const float wpx = 2.0f * (float)(wxg * WINN + WINN / 2) / (float)WW - 1.0f;
        const float wpy = 2.0f * (float)(hy  * WINN + WINN / 2) / (float)HH - 1.0f;

        float4 o;
        o.x = wpx;
        o.y = wpy;
        o.z = vx / 48.0f + wpx;                 // CENTER_REL = [48,48]
        o.w = vy / 48.0f + wpy;
        reinterpret_cast<float4*>(out)[(size_t)b * TN + hy * WSN + wxg] = o;
    }
}

extern "C" void kernel_launch(void* const* d_in, const int* in_sizes, int n_in,
                              void* d_out, int out_size, void* d_ws, size_t ws_size,
                              hipStream_t stream) {
    const float* imgs = (const float*)d_in[0];
    float* out = (float*)d_out;

    const int B = in_sizes[0] / (2 * HH * WW);  // 16
    const dim3 grid(B * HSN * SEGS);            // 1536 blocks
    SparseOptFlowLK_kernel<<<grid, 256, 0, stream>>>(imgs, out);
}